// Round 1
// baseline (216.466 us; speedup 1.0000x reference)
//
#include <hip/hip_runtime.h>

typedef __bf16 bf16x8 __attribute__((ext_vector_type(8)));
typedef float f32x4 __attribute__((ext_vector_type(4)));

#define MFMA16(a,b,c) __builtin_amdgcn_mfma_f32_16x16x32_bf16(a,b,c,0,0,0)

static __device__ __forceinline__ unsigned short f2bf(float f){
  union{float f;unsigned u;}v; v.f=f;
  unsigned u=v.u;
  u += 0x7fffu + ((u>>16)&1u);
  return (unsigned short)(u>>16);
}
static __device__ __forceinline__ float bf2f(unsigned short h){
  union{unsigned u;float f;}v; v.u=((unsigned)h)<<16; return v.f;
}

#define SCALE_QK 0.08838834764831845f

// ---------------------------------------------------------------------------
// Kernel 1: q/k/v projections (bf16 outputs) + combined per-key bias
//   t = blockIdx.y: 0 -> q = query@q_w + q_b   -> qp [b][n][d]
//                   1 -> k = key@k_w           -> kp [b][n][d]
//                   2 -> v = value@v_w + v_b   -> vpt [b][d][n]  (TRANSPOSED)
//                        + biasc[b][n] = value@vs_w + vs_b + att_bias
// ---------------------------------------------------------------------------
__global__ __launch_bounds__(256) void k_proj(
    const float* __restrict__ query, const float* __restrict__ key,
    const float* __restrict__ value, const float* __restrict__ att_bias,
    const float* __restrict__ q_w, const float* __restrict__ q_b,
    const float* __restrict__ k_w, const float* __restrict__ v_w,
    const float* __restrict__ v_b, const float* __restrict__ vs_w,
    const float* __restrict__ vs_b,
    unsigned short* __restrict__ qp, unsigned short* __restrict__ kp,
    unsigned short* __restrict__ vpt, float* __restrict__ biasc)
{
  const int t = blockIdx.y;
  const float* X = (t==0) ? query : ((t==1) ? key : value);
  const float* W = (t==0) ? q_w  : ((t==1) ? k_w : v_w);
  const int tid = threadIdx.x;
  const int row0 = blockIdx.x * 64;

  __shared__ __align__(16) unsigned short Wt[128][136];  // [dout][din], +8 pad
  __shared__ __align__(16) unsigned short Xs[64][136];   // [row][din], +8 pad
  __shared__ float vsw_s[128];

  // stage W transposed into LDS as bf16 (thread-chunked reads, ~2-way write conflicts)
  #pragma unroll 4
  for (int i=0;i<16;i++){
    int idx = tid*64 + i*4;
    float4 v4 = *(const float4*)(W + idx);
    Wt[(idx+0)&127][(idx+0)>>7] = f2bf(v4.x);
    Wt[(idx+1)&127][(idx+1)>>7] = f2bf(v4.y);
    Wt[(idx+2)&127][(idx+2)>>7] = f2bf(v4.z);
    Wt[(idx+3)&127][(idx+3)>>7] = f2bf(v4.w);
  }
  // stage X tile (64 rows x 128), fp32 -> bf16
  {
    const float* Xb = X + (size_t)row0*128;
    #pragma unroll
    for (int i=0;i<8;i++){
      int f4 = i*256 + tid;
      int row = f4>>5, c4 = f4&31;
      float4 v = *(const float4*)(Xb + row*128 + c4*4);
      ushort4 h;
      h.x = f2bf(v.x); h.y = f2bf(v.y); h.z = f2bf(v.z); h.w = f2bf(v.w);
      *(ushort4*)&Xs[row][c4*4] = h;
    }
  }
  if (t==2 && tid<128) vsw_s[tid] = vs_w[tid];
  __syncthreads();

  const int w = tid>>6, lane = tid&63, lr = lane&15, lg = lane>>4;
  f32x4 acc[8];
  #pragma unroll
  for (int nt=0;nt<8;nt++) acc[nt] = (f32x4){0.f,0.f,0.f,0.f};
  #pragma unroll
  for (int kk=0;kk<4;kk++){
    bf16x8 a = *(const bf16x8*)&Xs[w*16+lr][kk*32+lg*8];
    #pragma unroll
    for (int nt=0;nt<8;nt++){
      bf16x8 bb = *(const bf16x8*)&Wt[nt*16+lr][kk*32+lg*8];
      acc[nt] = MFMA16(a,bb,acc[nt]);
    }
  }
  const float* bias = (t==0) ? q_b : ((t==2) ? v_b : (const float*)nullptr);
  #pragma unroll
  for (int nt=0;nt<8;nt++){
    int col = nt*16+lr;
    float bv = bias ? bias[col] : 0.f;
    #pragma unroll
    for (int r=0;r<4;r++){
      int row = row0 + w*16 + lg*4 + r;
      unsigned short h = f2bf(acc[nt][r] + bv);
      if (t==0)      qp[(size_t)row*128+col] = h;
      else if (t==1) kp[(size_t)row*128+col] = h;
      else {
        int bi = row>>12, n = row&4095;
        vpt[((size_t)bi*128+col)*4096 + n] = h;
      }
    }
  }
  if (t==2){
    // semantic scalar + att_bias -> biasc  (4 threads per row)
    int rl = tid>>2, part = tid&3;
    float s = 0.f;
    #pragma unroll
    for (int j=0;j<32;j++){
      int d = part*32+j;
      s += bf2f(Xs[rl][d]) * vsw_s[d];
    }
    s += __shfl_xor(s,1);
    s += __shfl_xor(s,2);
    if ((tid&3)==0){
      int rg = row0 + rl;
      biasc[rg] = s + vs_b[0] + att_bias[rg];
    }
  }
}

// ---------------------------------------------------------------------------
// Kernel 2: flash attention.  Grid (NQ/64, B), 4 waves x 16 q-rows each.
//   S = qp @ kp^T * SCALE + biasc[k] ; online softmax ; O += P @ V
//   op[b][n][d] (bf16) = normalized attention output
// ---------------------------------------------------------------------------
__global__ __launch_bounds__(256) void k_flash(
    const unsigned short* __restrict__ qp, const unsigned short* __restrict__ kp,
    const unsigned short* __restrict__ vpt, const float* __restrict__ biasc,
    unsigned short* __restrict__ op)
{
  const int b = blockIdx.y;
  const int q0 = blockIdx.x*64;
  const int tid = threadIdx.x;
  const int w = tid>>6, lane = tid&63, lr = lane&15, lg = lane>>4;

  __shared__ __align__(16) unsigned short Ks[64][136];   // [key][d], +8 pad
  __shared__ __align__(16) unsigned short Vs[128][72];   // [d][key], +8 pad
  __shared__ __align__(16) unsigned short Ps[64][72];    // [q][key], +8 pad

  // Q fragments in registers (16 q-rows per wave)
  bf16x8 qf[4];
  {
    const unsigned short* qrow = qp + ((size_t)(b*4096 + q0 + w*16 + lr))*128;
    #pragma unroll
    for (int kk=0;kk<4;kk++) qf[kk] = *(const bf16x8*)(qrow + kk*32 + lg*8);
  }

  float m_r[4], l_r[4];
  #pragma unroll
  for (int r=0;r<4;r++){ m_r[r] = -INFINITY; l_r[r] = 0.f; }
  f32x4 acc[8];
  #pragma unroll
  for (int nt=0;nt<8;nt++) acc[nt] = (f32x4){0.f,0.f,0.f,0.f};

  const unsigned short* kbase = kp + (size_t)b*4096*128;
  const unsigned short* vbase = vpt + (size_t)b*128*4096;
  const float* bbase = biasc + b*4096;

  for (int t=0;t<64;t++){
    const int k0 = t*64;
    __syncthreads();
    // stage K tile (contiguous 16KB, coalesced)
    {
      const unsigned short* src = kbase + (size_t)k0*128;
      #pragma unroll
      for (int i=0;i<4;i++){
        int e = tid*32 + i*8;
        uint4 v = *(const uint4*)(src + e);
        *(uint4*)&Ks[e>>7][e&127] = v;
      }
    }
    // stage V^T tile (rows of vpt, 64B per thread)
    {
      int d = tid>>1, koff = (tid&1)*32;
      const unsigned short* src = vbase + (size_t)d*4096 + k0 + koff;
      #pragma unroll
      for (int i=0;i<4;i++){
        uint4 v = *(const uint4*)(src + i*8);
        *(uint4*)&Vs[d][koff + i*8] = v;
      }
    }
    __syncthreads();

    // ---- QK^T: 16 q-rows x 64 keys, contraction over D=128
    f32x4 sc[4];
    #pragma unroll
    for (int nt=0;nt<4;nt++) sc[nt] = (f32x4){0.f,0.f,0.f,0.f};
    #pragma unroll
    for (int kk=0;kk<4;kk++){
      #pragma unroll
      for (int nt=0;nt<4;nt++){
        bf16x8 kf = *(const bf16x8*)&Ks[nt*16+lr][kk*32+lg*8];
        sc[nt] = MFMA16(qf[kk], kf, sc[nt]);
      }
    }
    float s[4][4];
    #pragma unroll
    for (int nt=0;nt<4;nt++){
      float bs = bbase[k0 + nt*16 + lr];
      #pragma unroll
      for (int r=0;r<4;r++) s[nt][r] = sc[nt][r]*SCALE_QK + bs;
    }
    // ---- online softmax (rows split across 16-lane groups)
    float mt[4];
    #pragma unroll
    for (int r=0;r<4;r++) mt[r] = fmaxf(fmaxf(s[0][r],s[1][r]),fmaxf(s[2][r],s[3][r]));
    #pragma unroll
    for (int r=0;r<4;r++){
      mt[r] = fmaxf(mt[r], __shfl_xor(mt[r],1));
      mt[r] = fmaxf(mt[r], __shfl_xor(mt[r],2));
      mt[r] = fmaxf(mt[r], __shfl_xor(mt[r],4));
      mt[r] = fmaxf(mt[r], __shfl_xor(mt[r],8));
    }
    float corr[4];
    #pragma unroll
    for (int r=0;r<4;r++){
      float mn = fmaxf(m_r[r], mt[r]);
      corr[r] = __expf(m_r[r]-mn);
      m_r[r] = mn;
    }
    float ps[4][4], rs[4];
    #pragma unroll
    for (int r=0;r<4;r++) rs[r]=0.f;
    #pragma unroll
    for (int nt=0;nt<4;nt++){
      #pragma unroll
      for (int r=0;r<4;r++){
        ps[nt][r] = __expf(s[nt][r]-m_r[r]);
        rs[r] += ps[nt][r];
      }
    }
    #pragma unroll
    for (int r=0;r<4;r++){
      rs[r] += __shfl_xor(rs[r],1);
      rs[r] += __shfl_xor(rs[r],2);
      rs[r] += __shfl_xor(rs[r],4);
      rs[r] += __shfl_xor(rs[r],8);
      l_r[r] = l_r[r]*corr[r] + rs[r];
    }
    #pragma unroll
    for (int nt=0;nt<8;nt++){
      #pragma unroll
      for (int r=0;r<4;r++) acc[nt][r] *= corr[r];
    }
    // ---- P to LDS (wave-private rows; no barrier needed)
    #pragma unroll
    for (int nt=0;nt<4;nt++){
      #pragma unroll
      for (int r=0;r<4;r++)
        Ps[w*16 + lg*4 + r][nt*16 + lr] = f2bf(ps[nt][r]);
    }
    // ---- PV: contraction over 64 keys
    #pragma unroll
    for (int kk=0;kk<2;kk++){
      bf16x8 pf = *(const bf16x8*)&Ps[w*16+lr][kk*32+lg*8];
      #pragma unroll
      for (int nt=0;nt<8;nt++){
        bf16x8 vf = *(const bf16x8*)&Vs[nt*16+lr][kk*32+lg*8];
        acc[nt] = MFMA16(pf, vf, acc[nt]);
      }
    }
  }
  // epilogue: normalize, store bf16
  #pragma unroll
  for (int nt=0;nt<8;nt++){
    int col = nt*16+lr;
    #pragma unroll
    for (int r=0;r<4;r++){
      int row = q0 + w*16 + lg*4 + r;
      float o = acc[nt][r] / l_r[r];
      op[((size_t)(b*4096+row))*128 + col] = f2bf(o);
    }
  }
}

// ---------------------------------------------------------------------------
// Kernel 3: out = op @ p_w + p_b   (fp32 output)
// ---------------------------------------------------------------------------
__global__ __launch_bounds__(256) void k_outproj(
    const unsigned short* __restrict__ xin, const float* __restrict__ p_w,
    const float* __restrict__ p_b, float* __restrict__ out)
{
  const int tid = threadIdx.x;
  const int row0 = blockIdx.x*64;
  __shared__ __align__(16) unsigned short Wt[128][136];
  __shared__ __align__(16) unsigned short Xs[64][136];

  #pragma unroll 4
  for (int i=0;i<16;i++){
    int idx = tid*64 + i*4;
    float4 v4 = *(const float4*)(p_w + idx);
    Wt[(idx+0)&127][(idx+0)>>7] = f2bf(v4.x);
    Wt[(idx+1)&127][(idx+1)>>7] = f2bf(v4.y);
    Wt[(idx+2)&127][(idx+2)>>7] = f2bf(v4.z);
    Wt[(idx+3)&127][(idx+3)>>7] = f2bf(v4.w);
  }
  {
    const unsigned short* src = xin + (size_t)row0*128;
    #pragma unroll
    for (int i=0;i<4;i++){
      int e = tid*32 + i*8;
      uint4 v = *(const uint4*)(src + e);
      *(uint4*)&Xs[e>>7][e&127] = v;
    }
  }
  __syncthreads();

  const int w=tid>>6, lane=tid&63, lr=lane&15, lg=lane>>4;
  f32x4 acc[8];
  #pragma unroll
  for (int nt=0;nt<8;nt++) acc[nt] = (f32x4){0.f,0.f,0.f,0.f};
  #pragma unroll
  for (int kk=0;kk<4;kk++){
    bf16x8 a = *(const bf16x8*)&Xs[w*16+lr][kk*32+lg*8];
    #pragma unroll
    for (int nt=0;nt<8;nt++){
      bf16x8 bb = *(const bf16x8*)&Wt[nt*16+lr][kk*32+lg*8];
      acc[nt] = MFMA16(a,bb,acc[nt]);
    }
  }
  #pragma unroll
  for (int nt=0;nt<8;nt++){
    int col = nt*16+lr;
    float pb = p_b[col];
    #pragma unroll
    for (int r=0;r<4;r++){
      int row = row0 + w*16 + lg*4 + r;
      out[(size_t)row*128+col] = acc[nt][r] + pb;
    }
  }
}

extern "C" void kernel_launch(void* const* d_in, const int* in_sizes, int n_in,
                              void* d_out, int out_size, void* d_ws, size_t ws_size,
                              hipStream_t stream) {
  (void)in_sizes; (void)n_in; (void)out_size; (void)ws_size;
  const float* query    = (const float*)d_in[0];
  const float* key      = (const float*)d_in[1];
  const float* value    = (const float*)d_in[2];
  const float* att_bias = (const float*)d_in[3];
  const float* q_w = (const float*)d_in[4];
  const float* q_b = (const float*)d_in[5];
  const float* k_w = (const float*)d_in[6];
  const float* v_w = (const float*)d_in[7];
  const float* v_b = (const float*)d_in[8];
  const float* vs_w = (const float*)d_in[9];
  const float* vs_b = (const float*)d_in[10];
  const float* p_w = (const float*)d_in[11];
  const float* p_b = (const float*)d_in[12];

  char* ws = (char*)d_ws;
  unsigned short* qp   = (unsigned short*)(ws);             // 4 MB
  unsigned short* kp   = (unsigned short*)(ws + 4194304);   // 4 MB
  unsigned short* vpt  = (unsigned short*)(ws + 8388608);   // 4 MB  [b][d][n]
  float*          biasc= (float*)(ws + 12582912);           // 64 KB
  unsigned short* op   = (unsigned short*)(ws + 12648448);  // 4 MB

  hipLaunchKernelGGL(k_proj, dim3(256,3), dim3(256), 0, stream,
    query,key,value,att_bias,q_w,q_b,k_w,v_w,v_b,vs_w,vs_b,qp,kp,vpt,biasc);
  hipLaunchKernelGGL(k_flash, dim3(64,4), dim3(256), 0, stream,
    qp,kp,vpt,biasc,op);
  hipLaunchKernelGGL(k_outproj, dim3(256), dim3(256), 0, stream,
    op,p_w,p_b,(float*)d_out);
}

// Round 2
// 124.952 us; speedup vs baseline: 1.7324x; 1.7324x over previous
//
#include <hip/hip_runtime.h>

typedef __bf16 bf16x8 __attribute__((ext_vector_type(8)));
typedef float f32x4 __attribute__((ext_vector_type(4)));

#define MFMA16(a,b,c) __builtin_amdgcn_mfma_f32_16x16x32_bf16(a,b,c,0,0,0)

static __device__ __forceinline__ unsigned short f2bf(float f){
  union{float f;unsigned u;}v; v.f=f;
  unsigned u=v.u;
  u += 0x7fffu + ((u>>16)&1u);
  return (unsigned short)(u>>16);
}
static __device__ __forceinline__ float bf2f(unsigned short h){
  union{unsigned u;float f;}v; v.u=((unsigned)h)<<16; return v.f;
}

#define SCALE_QK 0.08838834764831845f

// XOR swizzles (short-index) for bank-conflict-free ds_read_b128:
//   128-col row-major bf16 tile (256B stride): byte ^= (row&7)<<4
#define SWZ128(r,c) (((r)<<7) + ((c) ^ (((r)&7)<<3)))
//   64-col row-major bf16 tile (128B stride)
#define SWZ64(r,c)  (((r)<<6) + ((c) ^ (((r)&7)<<3)))

// ---------------------------------------------------------------------------
// Kernel 1: q/k/v projections (bf16 outputs) + combined per-key bias
// ---------------------------------------------------------------------------
__global__ __launch_bounds__(256) void k_proj(
    const float* __restrict__ query, const float* __restrict__ key,
    const float* __restrict__ value, const float* __restrict__ att_bias,
    const float* __restrict__ q_w, const float* __restrict__ q_b,
    const float* __restrict__ k_w, const float* __restrict__ v_w,
    const float* __restrict__ v_b, const float* __restrict__ vs_w,
    const float* __restrict__ vs_b,
    unsigned short* __restrict__ qp, unsigned short* __restrict__ kp,
    unsigned short* __restrict__ vpt, float* __restrict__ biasc)
{
  const int t = blockIdx.y;
  const float* X = (t==0) ? query : ((t==1) ? key : value);
  const float* W = (t==0) ? q_w  : ((t==1) ? k_w : v_w);
  const int tid = threadIdx.x;
  const int row0 = blockIdx.x * 64;

  __shared__ __align__(16) unsigned short Wt[128][136];  // [dout][din], +8 pad
  __shared__ __align__(16) unsigned short Xs[64][136];   // [row][din], +8 pad
  __shared__ float vsw_s[128];

  #pragma unroll 4
  for (int i=0;i<16;i++){
    int idx = tid*64 + i*4;
    float4 v4 = *(const float4*)(W + idx);
    Wt[(idx+0)&127][(idx+0)>>7] = f2bf(v4.x);
    Wt[(idx+1)&127][(idx+1)>>7] = f2bf(v4.y);
    Wt[(idx+2)&127][(idx+2)>>7] = f2bf(v4.z);
    Wt[(idx+3)&127][(idx+3)>>7] = f2bf(v4.w);
  }
  {
    const float* Xb = X + (size_t)row0*128;
    #pragma unroll
    for (int i=0;i<8;i++){
      int f4 = i*256 + tid;
      int row = f4>>5, c4 = f4&31;
      float4 v = *(const float4*)(Xb + row*128 + c4*4);
      ushort4 h;
      h.x = f2bf(v.x); h.y = f2bf(v.y); h.z = f2bf(v.z); h.w = f2bf(v.w);
      *(ushort4*)&Xs[row][c4*4] = h;
    }
  }
  if (t==2 && tid<128) vsw_s[tid] = vs_w[tid];
  __syncthreads();

  const int w = tid>>6, lane = tid&63, lr = lane&15, lg = lane>>4;
  f32x4 acc[8];
  #pragma unroll
  for (int nt=0;nt<8;nt++) acc[nt] = (f32x4){0.f,0.f,0.f,0.f};
  #pragma unroll
  for (int kk=0;kk<4;kk++){
    bf16x8 a = *(const bf16x8*)&Xs[w*16+lr][kk*32+lg*8];
    #pragma unroll
    for (int nt=0;nt<8;nt++){
      bf16x8 bb = *(const bf16x8*)&Wt[nt*16+lr][kk*32+lg*8];
      acc[nt] = MFMA16(a,bb,acc[nt]);
    }
  }
  const float* bias = (t==0) ? q_b : ((t==2) ? v_b : (const float*)nullptr);
  #pragma unroll
  for (int nt=0;nt<8;nt++){
    int col = nt*16+lr;
    float bv = bias ? bias[col] : 0.f;
    #pragma unroll
    for (int r=0;r<4;r++){
      int row = row0 + w*16 + lg*4 + r;
      unsigned short h = f2bf(acc[nt][r] + bv);
      if (t==0)      qp[(size_t)row*128+col] = h;
      else if (t==1) kp[(size_t)row*128+col] = h;
      else {
        int bi = row>>12, n = row&4095;
        vpt[((size_t)bi*128+col)*4096 + n] = h;
      }
    }
  }
  if (t==2){
    int rl = tid>>2, part = tid&3;
    float s = 0.f;
    #pragma unroll
    for (int j=0;j<32;j++){
      int d = part*32+j;
      s += bf2f(Xs[rl][d]) * vsw_s[d];
    }
    s += __shfl_xor(s,1);
    s += __shfl_xor(s,2);
    if ((tid&3)==0){
      int rg = row0 + rl;
      biasc[rg] = s + vs_b[0] + att_bias[rg];
    }
  }
}

// ---------------------------------------------------------------------------
// Kernel 2: flash attention, KV-split 4-way.
//   Grid (NQ/64, 4 splits, B). Each block: 64 q-rows x 1024 keys (16 tiles).
//   Writes normalized partial O (bf16) + per-row (m,l) fp32.
//   LDS = 16+16+8 = 40KB exactly -> 4 blocks/CU = 16 waves/CU.
// ---------------------------------------------------------------------------
__global__ __launch_bounds__(256,4) void k_flash(
    const unsigned short* __restrict__ qp, const unsigned short* __restrict__ kp,
    const unsigned short* __restrict__ vpt, const float* __restrict__ biasc,
    unsigned short* __restrict__ opart, float* __restrict__ ml)
{
  const int b = blockIdx.z, split = blockIdx.y;
  const int q0 = blockIdx.x*64;
  const int tid = threadIdx.x;
  const int w = tid>>6, lane = tid&63, lr = lane&15, lg = lane>>4;

  __shared__ __align__(16) unsigned short Ks[64*128];   // [key][d], swizzled
  __shared__ __align__(16) unsigned short Vs[128*64];   // [d][key], swizzled
  __shared__ __align__(16) unsigned short Ps[64*64];    // [q][key], swizzled

  bf16x8 qf[4];
  {
    const unsigned short* qrow = qp + ((size_t)(b*4096 + q0 + w*16 + lr))*128;
    #pragma unroll
    for (int kk=0;kk<4;kk++) qf[kk] = *(const bf16x8*)(qrow + kk*32 + lg*8);
  }

  float m_r[4], l_r[4];
  #pragma unroll
  for (int r=0;r<4;r++){ m_r[r] = -INFINITY; l_r[r] = 0.f; }
  f32x4 acc[8];
  #pragma unroll
  for (int nt=0;nt<8;nt++) acc[nt] = (f32x4){0.f,0.f,0.f,0.f};

  const unsigned short* kbase = kp  + (size_t)b*4096*128 + (size_t)split*1024*128;
  const unsigned short* vbase = vpt + (size_t)b*128*4096 + split*1024;
  const float* bbase = biasc + b*4096 + split*1024;

  for (int t=0;t<16;t++){
    const int k0 = t*64;
    __syncthreads();
    // stage K tile (contiguous 16KB, coalesced, swizzled writes)
    {
      const unsigned short* src = kbase + (size_t)k0*128;
      #pragma unroll
      for (int i=0;i<4;i++){
        int e = tid*32 + i*8;
        int row = e>>7, col = e&127;
        *(uint4*)&Ks[SWZ128(row,col)] = *(const uint4*)(src + e);
      }
    }
    // stage V^T tile (swizzled writes)
    {
      int d = tid>>1, koff = (tid&1)*32;
      const unsigned short* src = vbase + (size_t)d*4096 + k0 + koff;
      #pragma unroll
      for (int i=0;i<4;i++)
        *(uint4*)&Vs[SWZ64(d, koff + i*8)] = *(const uint4*)(src + i*8);
    }
    __syncthreads();

    // ---- QK^T
    f32x4 sc[4];
    #pragma unroll
    for (int nt=0;nt<4;nt++) sc[nt] = (f32x4){0.f,0.f,0.f,0.f};
    #pragma unroll
    for (int kk=0;kk<4;kk++){
      #pragma unroll
      for (int nt=0;nt<4;nt++){
        bf16x8 kf = *(const bf16x8*)&Ks[SWZ128(nt*16+lr, kk*32+lg*8)];
        sc[nt] = MFMA16(qf[kk], kf, sc[nt]);
      }
    }
    float s[4][4];
    #pragma unroll
    for (int nt=0;nt<4;nt++){
      float bs = bbase[k0 + nt*16 + lr];
      #pragma unroll
      for (int r=0;r<4;r++) s[nt][r] = sc[nt][r]*SCALE_QK + bs;
    }
    // ---- online softmax
    float mt[4];
    #pragma unroll
    for (int r=0;r<4;r++) mt[r] = fmaxf(fmaxf(s[0][r],s[1][r]),fmaxf(s[2][r],s[3][r]));
    #pragma unroll
    for (int r=0;r<4;r++){
      mt[r] = fmaxf(mt[r], __shfl_xor(mt[r],1));
      mt[r] = fmaxf(mt[r], __shfl_xor(mt[r],2));
      mt[r] = fmaxf(mt[r], __shfl_xor(mt[r],4));
      mt[r] = fmaxf(mt[r], __shfl_xor(mt[r],8));
    }
    float corr[4];
    #pragma unroll
    for (int r=0;r<4;r++){
      float mn = fmaxf(m_r[r], mt[r]);
      corr[r] = __expf(m_r[r]-mn);
      m_r[r] = mn;
    }
    float ps[4][4], rs[4];
    #pragma unroll
    for (int r=0;r<4;r++) rs[r]=0.f;
    #pragma unroll
    for (int nt=0;nt<4;nt++){
      #pragma unroll
      for (int r=0;r<4;r++){
        ps[nt][r] = __expf(s[nt][r]-m_r[r]);
        rs[r] += ps[nt][r];
      }
    }
    #pragma unroll
    for (int r=0;r<4;r++){
      rs[r] += __shfl_xor(rs[r],1);
      rs[r] += __shfl_xor(rs[r],2);
      rs[r] += __shfl_xor(rs[r],4);
      rs[r] += __shfl_xor(rs[r],8);
      l_r[r] = l_r[r]*corr[r] + rs[r];
    }
    #pragma unroll
    for (int nt=0;nt<8;nt++){
      #pragma unroll
      for (int r=0;r<4;r++) acc[nt][r] *= corr[r];
    }
    // ---- P to LDS (wave-private rows)
    #pragma unroll
    for (int nt=0;nt<4;nt++){
      #pragma unroll
      for (int r=0;r<4;r++)
        Ps[SWZ64(w*16 + lg*4 + r, nt*16 + lr)] = f2bf(ps[nt][r]);
    }
    // ---- PV
    #pragma unroll
    for (int kk=0;kk<2;kk++){
      bf16x8 pf = *(const bf16x8*)&Ps[SWZ64(w*16+lr, kk*32+lg*8)];
      #pragma unroll
      for (int nt=0;nt<8;nt++){
        bf16x8 vf = *(const bf16x8*)&Vs[SWZ64(nt*16+lr, kk*32+lg*8)];
        acc[nt] = MFMA16(pf, vf, acc[nt]);
      }
    }
  }
  // epilogue: normalized partial (bf16) + m,l
  const size_t rowbase = (size_t)split*16384 + (size_t)b*4096 + q0;
  #pragma unroll
  for (int nt=0;nt<8;nt++){
    int col = nt*16+lr;
    #pragma unroll
    for (int r=0;r<4;r++){
      int rowl = w*16 + lg*4 + r;
      opart[(rowbase + rowl)*128 + col] = f2bf(acc[nt][r] / l_r[r]);
    }
  }
  if (lr==0){
    #pragma unroll
    for (int r=0;r<4;r++){
      size_t rg = rowbase + w*16 + lg*4 + r;
      ml[rg*2]   = m_r[r];
      ml[rg*2+1] = l_r[r];
    }
  }
}

// ---------------------------------------------------------------------------
// Kernel 3: merge 4 KV-split partials + out-projection.
//   out = (sum_i w_i * Ohat_i) @ p_w + p_b
// ---------------------------------------------------------------------------
__global__ __launch_bounds__(256) void k_outproj(
    const unsigned short* __restrict__ opart, const float* __restrict__ ml,
    const float* __restrict__ p_w, const float* __restrict__ p_b,
    float* __restrict__ out)
{
  const int tid = threadIdx.x;
  const int row0 = blockIdx.x*64;   // global row in [0,16384)
  __shared__ __align__(16) unsigned short Wt[128][136];
  __shared__ __align__(16) unsigned short Xs[64][136];
  __shared__ float wmg[4][64];

  #pragma unroll 4
  for (int i=0;i<16;i++){
    int idx = tid*64 + i*4;
    float4 v4 = *(const float4*)(p_w + idx);
    Wt[(idx+0)&127][(idx+0)>>7] = f2bf(v4.x);
    Wt[(idx+1)&127][(idx+1)>>7] = f2bf(v4.y);
    Wt[(idx+2)&127][(idx+2)>>7] = f2bf(v4.z);
    Wt[(idx+3)&127][(idx+3)>>7] = f2bf(v4.w);
  }
  if (tid < 64){
    int row = row0 + tid;
    float m[4], l[4];
    #pragma unroll
    for (int i=0;i<4;i++){
      m[i] = ml[((size_t)i*16384 + row)*2];
      l[i] = ml[((size_t)i*16384 + row)*2 + 1];
    }
    float M = fmaxf(fmaxf(m[0],m[1]),fmaxf(m[2],m[3]));
    float wi[4], wsum = 0.f;
    #pragma unroll
    for (int i=0;i<4;i++){ wi[i] = __expf(m[i]-M)*l[i]; wsum += wi[i]; }
    float inv = 1.f/wsum;
    #pragma unroll
    for (int i=0;i<4;i++) wmg[i][tid] = wi[i]*inv;
  }
  __syncthreads();
  // stage merged X tile
  #pragma unroll
  for (int i=0;i<4;i++){
    int e = tid*32 + i*8;
    int row = e>>7, col = e&127;
    float a8[8];
    #pragma unroll
    for (int j=0;j<8;j++) a8[j] = 0.f;
    #pragma unroll
    for (int s=0;s<4;s++){
      uint4 v = *(const uint4*)(opart + ((size_t)s*16384 + row0 + row)*128 + col);
      float wv = wmg[s][row];
      const unsigned short* hp = (const unsigned short*)&v;
      #pragma unroll
      for (int j=0;j<8;j++) a8[j] += wv * bf2f(hp[j]);
    }
    unsigned short h8[8];
    #pragma unroll
    for (int j=0;j<8;j++) h8[j] = f2bf(a8[j]);
    *(uint4*)&Xs[row][col] = *(const uint4*)h8;
  }
  __syncthreads();

  const int w=tid>>6, lane=tid&63, lr=lane&15, lg=lane>>4;
  f32x4 acc[8];
  #pragma unroll
  for (int nt=0;nt<8;nt++) acc[nt] = (f32x4){0.f,0.f,0.f,0.f};
  #pragma unroll
  for (int kk=0;kk<4;kk++){
    bf16x8 a = *(const bf16x8*)&Xs[w*16+lr][kk*32+lg*8];
    #pragma unroll
    for (int nt=0;nt<8;nt++){
      bf16x8 bb = *(const bf16x8*)&Wt[nt*16+lr][kk*32+lg*8];
      acc[nt] = MFMA16(a,bb,acc[nt]);
    }
  }
  #pragma unroll
  for (int nt=0;nt<8;nt++){
    int col = nt*16+lr;
    float pb = p_b[col];
    #pragma unroll
    for (int r=0;r<4;r++){
      int row = row0 + w*16 + lg*4 + r;
      out[(size_t)row*128+col] = acc[nt][r] + pb;
    }
  }
}

extern "C" void kernel_launch(void* const* d_in, const int* in_sizes, int n_in,
                              void* d_out, int out_size, void* d_ws, size_t ws_size,
                              hipStream_t stream) {
  (void)in_sizes; (void)n_in; (void)out_size; (void)ws_size;
  const float* query    = (const float*)d_in[0];
  const float* key      = (const float*)d_in[1];
  const float* value    = (const float*)d_in[2];
  const float* att_bias = (const float*)d_in[3];
  const float* q_w = (const float*)d_in[4];
  const float* q_b = (const float*)d_in[5];
  const float* k_w = (const float*)d_in[6];
  const float* v_w = (const float*)d_in[7];
  const float* v_b = (const float*)d_in[8];
  const float* vs_w = (const float*)d_in[9];
  const float* vs_b = (const float*)d_in[10];
  const float* p_w = (const float*)d_in[11];
  const float* p_b = (const float*)d_in[12];

  char* ws = (char*)d_ws;
  unsigned short* qp    = (unsigned short*)(ws);             // 4 MB
  unsigned short* kp    = (unsigned short*)(ws + 4194304);   // 4 MB
  unsigned short* vpt   = (unsigned short*)(ws + 8388608);   // 4 MB  [b][d][n]
  float*          biasc = (float*)(ws + 12582912);           // 64 KB
  unsigned short* opart = (unsigned short*)(ws + 12648448);  // 16 MB [split][b][q][d]
  float*          ml    = (float*)(ws + 29425664);           // 512 KB [split][b*q][2]

  hipLaunchKernelGGL(k_proj, dim3(256,3), dim3(256), 0, stream,
    query,key,value,att_bias,q_w,q_b,k_w,v_w,v_b,vs_w,vs_b,qp,kp,vpt,biasc);
  hipLaunchKernelGGL(k_flash, dim3(64,4,4), dim3(256), 0, stream,
    qp,kp,vpt,biasc,opart,ml);
  hipLaunchKernelGGL(k_outproj, dim3(256), dim3(256), 0, stream,
    opart,ml,p_w,p_b,(float*)d_out);
}